// Round 1
// baseline (17925.514 us; speedup 1.0000x reference)
//
#include <hip/hip_runtime.h>

typedef unsigned short u16;
typedef unsigned int   u32;
typedef short bf16x8 __attribute__((ext_vector_type(8)));
typedef float f32x4  __attribute__((ext_vector_type(4)));
typedef float f32x16 __attribute__((ext_vector_type(16)));

// Problem sizes
static constexpr int BB   = 64;    // batch
static constexpr int TT   = 256;   // seq len
static constexpr int HH   = 1024;  // hidden
static constexpr int NBLK = 64;    // scan grid

// Workspace layout (bytes), all 256-aligned. Total ~235.4 MB.
static constexpr size_t OFF_WIHT = 0;           // bf16 [2][4096(n_re)][1024(k)]
static constexpr size_t OFF_WHHT = 16777216;    // bf16 [2][4096(n_re)][1024(k)]
static constexpr size_t OFF_BIAS = 33554432;    // f32  [2][4096(n_re)]  (bih+bhh)
static constexpr size_t OFF_XBF  = 33587200;    // bf16 [16384][1024]
static constexpr size_t OFF_Y0   = 67141632;    // bf16 [16384][1024]
static constexpr size_t OFF_GT   = 100696064;   // bf16 [64 blk][256 t][64 b][64 j]
static constexpr size_t OFF_HBUF = 234913792;   // bf16 [2][64][1024]
static constexpr size_t OFF_CBUF = 235175936;   // f32  [64][1024]
static constexpr size_t OFF_BAR  = 235438080;   // int barrier counter

__device__ __forceinline__ u16 f2bf(float f) {
  u32 u = __float_as_uint(f);
  u32 r = (u + 0x7fffu + ((u >> 16) & 1u)) >> 16;  // RNE
  return (u16)r;
}
__device__ __forceinline__ float b2f(u16 h) {
  return __uint_as_float(((u32)h) << 16);
}
__device__ __forceinline__ float sigm(float z) { return 1.f / (1.f + __expf(-z)); }
__device__ __forceinline__ float tanh_f(float z) {
  float e = __expf(fminf(fmaxf(2.f * z, -80.f), 80.f));
  return (e - 1.f) / (e + 1.f);
}

// column reorder: orig gate col n = g*1024+u  ->  n_re = (u>>4)*64 + g*16 + (u&15)
// so scan block bid owns hidden units [16*bid,16*bid+16) as contiguous rows [64*bid,64*bid+64)

// ---------------- prep: transpose+reorder weights to bf16 [n_re][k] ----------------
__global__ void prep_transpose(const float* __restrict__ Wih, const float* __restrict__ Whh,
                               u16* __restrict__ WihT, u16* __restrict__ WhhT) {
  __shared__ float tr[64][65];
  const int kt = blockIdx.x;            // 0..15
  const int nt = blockIdx.y;            // 0..63
  const int z  = blockIdx.z;            // 0:Wih L0, 1:Wih L1, 2:Whh L0, 3:Whh L1
  const float* src = (z < 2 ? Wih : Whh) + (size_t)(z & 1) * (1024 * 4096);
  u16* dst = (z < 2 ? WihT : WhhT) + (size_t)(z & 1) * (4096 * 1024);
  const int tid = threadIdx.x;
  const int k0 = kt << 6, n0 = nt << 6;
#pragma unroll
  for (int i = 0; i < 16; ++i) {
    int e = (i << 8) + tid;
    int kk = e >> 6, nn = e & 63;
    tr[kk][nn] = src[(size_t)(k0 + kk) * 4096 + n0 + nn];
  }
  __syncthreads();
#pragma unroll
  for (int i = 0; i < 16; ++i) {
    int e = (i << 8) + tid;
    int nn = e >> 6, kk = e & 63;
    int n = n0 + nn;
    int u = n & 1023, g = n >> 10;
    int n_re = ((u >> 4) << 6) + (g << 4) + (u & 15);
    dst[(size_t)n_re * 1024 + k0 + kk] = f2bf(tr[kk][nn]);
  }
}

__global__ void prep_bias(const float* __restrict__ bih, const float* __restrict__ bhh,
                          float* __restrict__ biasr) {
  int i = blockIdx.x * 256 + threadIdx.x;   // 0..8191
  int l = i >> 12, n = i & 4095;
  int u = n & 1023, g = n >> 10;
  int n_re = ((u >> 4) << 6) + (g << 4) + (u & 15);
  biasr[l * 4096 + n_re] = bih[i] + bhh[i];
}

__global__ void cast_x(const float* __restrict__ x, u16* __restrict__ xb) {
  size_t i = ((size_t)blockIdx.x * 256 + threadIdx.x) * 4;
  float4 v = *(const float4*)(x + i);
  uint2 o;
  o.x = (u32)f2bf(v.x) | ((u32)f2bf(v.y) << 16);
  o.y = (u32)f2bf(v.z) | ((u32)f2bf(v.w) << 16);
  *(uint2*)(xb + i) = o;
}

// ---------------- big GEMM: gates_pre = A[16384,1024] @ W^T[n_re][k] + bias ----------------
// 128x128 tile, BK=64, 4 waves (2x2 quadrants of 64x64), 16x16x32 bf16 MFMA.
__global__ __launch_bounds__(256)
void gemm_gates(const u16* __restrict__ A, const u16* __restrict__ Wt,
                const float* __restrict__ bias, u16* __restrict__ Gout) {
  __shared__ __align__(16) u16 sm[16384];       // Ash[128][64] + Bsh[128][64] (32KB)
  u16* Ash = sm;
  u16* Bsh = sm + 8192;
  float* LDSf = (float*)sm;                     // reused in epilogue: [64][128] f32
  const int tid = threadIdx.x;
  const int r0 = blockIdx.x << 7;
  const int n0 = blockIdx.y << 7;
  const int lane = tid & 63, w = tid >> 6, wm = w >> 1, wn = w & 1;
  f32x4 acc[4][4] = {};
  for (int kt = 0; kt < 16; ++kt) {
    const int k0 = kt << 6;
#pragma unroll
    for (int i = 0; i < 4; ++i) {               // stage A,B tiles (XOR-swizzled 16B chunks)
      int c = tid + (i << 8);
      int row = c >> 3, s = c & 7;
      int4 va = *(const int4*)(A  + (size_t)(r0 + row) * 1024 + k0 + (s << 3));
      int4 vb = *(const int4*)(Wt + (size_t)(n0 + row) * 1024 + k0 + (s << 3));
      *(int4*)(Ash + (row << 6) + (((s ^ (row & 7))) << 3)) = va;
      *(int4*)(Bsh + (row << 6) + (((s ^ (row & 7))) << 3)) = vb;
    }
    __syncthreads();
#pragma unroll
    for (int ks = 0; ks < 2; ++ks) {
      bf16x8 af[4], bfr[4];
#pragma unroll
      for (int mt = 0; mt < 4; ++mt) {
        int row = (wm << 6) + (mt << 4) + (lane & 15);
        int ch = ((ks << 2) + (lane >> 4)) ^ (row & 7);
        af[mt] = *(const bf16x8*)(Ash + (row << 6) + (ch << 3));
      }
#pragma unroll
      for (int nt2 = 0; nt2 < 4; ++nt2) {
        int row = (wn << 6) + (nt2 << 4) + (lane & 15);
        int ch = ((ks << 2) + (lane >> 4)) ^ (row & 7);
        bfr[nt2] = *(const bf16x8*)(Bsh + (row << 6) + (ch << 3));
      }
#pragma unroll
      for (int mt = 0; mt < 4; ++mt)
#pragma unroll
        for (int nt2 = 0; nt2 < 4; ++nt2)
          acc[mt][nt2] = __builtin_amdgcn_mfma_f32_16x16x32_bf16(af[mt], bfr[nt2], acc[mt][nt2], 0, 0, 0);
    }
    __syncthreads();
  }
  // epilogue: bias add, bf16 pack, coalesced store to GATES[bk][t][b][j] via LDS repack
  for (int p = 0; p < 2; ++p) {
    if (wm == p) {
#pragma unroll
      for (int mt = 0; mt < 4; ++mt)
#pragma unroll
        for (int nt2 = 0; nt2 < 4; ++nt2)
#pragma unroll
          for (int r = 0; r < 4; ++r) {
            int lrow = (mt << 4) + ((lane >> 4) << 2) + r;
            int col = (wn << 6) + (nt2 << 4) + (lane & 15);
            LDSf[(lrow << 7) + col] = acc[mt][nt2][r];
          }
    }
    __syncthreads();
    {
      int row = tid >> 2, quad = tid & 3;
      int rg = r0 + (p << 6) + row;
      int bb = rg >> 8, tt = rg & 255;
      union { u16 s[32]; int4 v[4]; } ob;
#pragma unroll
      for (int cc = 0; cc < 32; ++cc) {
        int col = (quad << 5) + cc;
        ob.s[cc] = f2bf(LDSf[(row << 7) + col] + bias[n0 + col]);
      }
      size_t bk = (size_t)((n0 + (quad << 5)) >> 6);
      u16* dst = Gout + bk * 1048576 + ((size_t)tt * 64 + bb) * 64 + ((quad & 1) << 5);
#pragma unroll
      for (int c4 = 0; c4 < 4; ++c4) *(int4*)(dst + (c4 << 3)) = ob.v[c4];
    }
    __syncthreads();
  }
}

// ---------------- persistent scan with device-wide barrier ----------------
__device__ __forceinline__ void grid_barrier(int* bar, int target) {
  __syncthreads();
  __threadfence();                 // release: flush h/c/y writes (cross-XCD)
  if (threadIdx.x == 0) {
    atomicAdd(bar, 1);
    while (__hip_atomic_load(bar, __ATOMIC_RELAXED, __HIP_MEMORY_SCOPE_AGENT) < target)
      __builtin_amdgcn_s_sleep(2);
  }
  __syncthreads();
  __threadfence();                 // acquire: invalidate stale cached h
}

// 64 blocks x 512 thr (8 waves). Block bid owns hidden units [16*bid,16*bid+16)
// = reordered gate cols [64*bid, 64*bid+64). Wave (kh,mh,nt): 2-way split-K,
// [32 batch x 32 col] tile via mfma_f32_32x32x16_bf16. Combine in LDS, pointwise, barrier.
__global__ __launch_bounds__(512)
void lstm_scan(const u16* __restrict__ gatesAll, const u16* __restrict__ whht,
               u16* __restrict__ hbuf, float* __restrict__ cbuf,
               u16* __restrict__ ybf, float* __restrict__ yf32,
               float* __restrict__ states, int* __restrict__ bar) {
  __shared__ float Gsh[64][64];
  const int tid = threadIdx.x, bid = blockIdx.x;
  const int lane = tid & 63, w = tid >> 6;
  const int kh = w >> 2, mh = (w >> 1) & 1, ntc = w & 1;
  const int mrow = (mh << 5) + (lane & 31);                 // batch row (A "m")
  const int kofs = (kh << 9) + ((lane >> 5) << 3);
  const u16* bbase = whht + (size_t)((bid << 6) + (ntc << 5) + (lane & 31)) * 1024 + kofs;
  const u16* gblk = gatesAll + (size_t)bid * 1048576;
  const int col = (ntc << 5) + (lane & 31);                 // C/D col = lane&31
  const int mb0 = (mh << 5) + ((lane >> 5) << 2);           // C/D row base
  int cur = 0;
  for (int t = 0; t < TT; ++t) {
    const u16* abase = hbuf + cur * 65536 + mrow * 1024 + kofs;
    f32x16 a0 = {}, a1 = {}, a2 = {}, a3 = {};
#pragma unroll 2
    for (int kk = 0; kk < 32; kk += 4) {
      bf16x8 va0 = *(const bf16x8*)(abase + (kk + 0) * 16);
      bf16x8 vb0 = *(const bf16x8*)(bbase + (kk + 0) * 16);
      bf16x8 va1 = *(const bf16x8*)(abase + (kk + 1) * 16);
      bf16x8 vb1 = *(const bf16x8*)(bbase + (kk + 1) * 16);
      bf16x8 va2 = *(const bf16x8*)(abase + (kk + 2) * 16);
      bf16x8 vb2 = *(const bf16x8*)(bbase + (kk + 2) * 16);
      bf16x8 va3 = *(const bf16x8*)(abase + (kk + 3) * 16);
      bf16x8 vb3 = *(const bf16x8*)(bbase + (kk + 3) * 16);
      a0 = __builtin_amdgcn_mfma_f32_32x32x16_bf16(va0, vb0, a0, 0, 0, 0);
      a1 = __builtin_amdgcn_mfma_f32_32x32x16_bf16(va1, vb1, a1, 0, 0, 0);
      a2 = __builtin_amdgcn_mfma_f32_32x32x16_bf16(va2, vb2, a2, 0, 0, 0);
      a3 = __builtin_amdgcn_mfma_f32_32x32x16_bf16(va3, vb3, a3, 0, 0, 0);
    }
    f32x16 acc = (a0 + a1) + (a2 + a3);
    // combine split-K halves
    if (kh == 0) {
#pragma unroll
      for (int r = 0; r < 16; ++r) Gsh[mb0 + (r & 3) + ((r >> 2) << 3)][col] = acc[r];
    }
    __syncthreads();
    if (kh == 1) {
#pragma unroll
      for (int r = 0; r < 16; ++r) Gsh[mb0 + (r & 3) + ((r >> 2) << 3)][col] += acc[r];
    }
    __syncthreads();
    // pointwise: 1024 (b, unit) pairs over 512 threads
    {
      const int bb = tid >> 3;
      const u16* g = gblk + ((size_t)t << 12) + (bb << 6);
#pragma unroll
      for (int q = 0; q < 2; ++q) {
        int uj = ((tid & 7) << 1) + q;
        float zi = Gsh[bb][uj]      + b2f(g[uj]);
        float zf = Gsh[bb][16 + uj] + b2f(g[16 + uj]);
        float zg = Gsh[bb][32 + uj] + b2f(g[32 + uj]);
        float zo = Gsh[bb][48 + uj] + b2f(g[48 + uj]);
        int u = (bid << 4) + uj;
        float co = cbuf[(bb << 10) + u];
        float cn = sigm(zf) * co + sigm(zi) * tanh_f(zg);
        float hn = sigm(zo) * tanh_f(cn);
        cbuf[(bb << 10) + u] = cn;
        hbuf[(cur ^ 1) * 65536 + (bb << 10) + u] = f2bf(hn);
        if (ybf)  ybf[((size_t)bb * 256 + t) * 1024 + u] = f2bf(hn);
        if (yf32) yf32[((size_t)bb * 256 + t) * 1024 + u] = hn;
        if (t == TT - 1) {
          states[(bb << 10) + u] = hn;
          states[65536 + (bb << 10) + u] = cn;
        }
      }
    }
    grid_barrier(bar, NBLK * (t + 1));
    cur ^= 1;
  }
}

extern "C" void kernel_launch(void* const* d_in, const int* in_sizes, int n_in,
                              void* d_out, int out_size, void* d_ws, size_t ws_size,
                              hipStream_t stream) {
  const float* x   = (const float*)d_in[0];
  const float* Wih = (const float*)d_in[1];
  const float* Whh = (const float*)d_in[2];
  const float* bih = (const float*)d_in[3];
  const float* bhh = (const float*)d_in[4];
  float* out = (float*)d_out;
  char* ws = (char*)d_ws;

  u16*   WihT  = (u16*)(ws + OFF_WIHT);
  u16*   WhhT  = (u16*)(ws + OFF_WHHT);
  float* BiasR = (float*)(ws + OFF_BIAS);
  u16*   Xbf   = (u16*)(ws + OFF_XBF);
  u16*   Y0    = (u16*)(ws + OFF_Y0);
  u16*   Gt    = (u16*)(ws + OFF_GT);
  u16*   Hbuf  = (u16*)(ws + OFF_HBUF);
  float* Cbuf  = (float*)(ws + OFF_CBUF);
  int*   Bar   = (int*)(ws + OFF_BAR);

  // zero h0, c0, barrier (ws is poisoned 0xAA before each call)
  hipMemsetAsync(ws + OFF_HBUF, 0, 524544, stream);

  prep_transpose<<<dim3(16, 64, 4), 256, 0, stream>>>(Wih, Whh, WihT, WhhT);
  prep_bias<<<32, 256, 0, stream>>>(bih, bhh, BiasR);
  cast_x<<<16384, 256, 0, stream>>>(x, Xbf);

  // ----- layer 0 -----
  gemm_gates<<<dim3(128, 32), 256, 0, stream>>>(Xbf, WihT, BiasR, Gt);
  lstm_scan<<<NBLK, 512, 0, stream>>>(Gt, WhhT, Hbuf, Cbuf, Y0, nullptr,
                                      out + 16777216, Bar);

  // ----- layer 1 -----
  hipMemsetAsync(ws + OFF_HBUF, 0, 524544, stream);
  gemm_gates<<<dim3(128, 32), 256, 0, stream>>>(Y0, WihT + 4194304, BiasR + 4096, Gt);
  lstm_scan<<<NBLK, 512, 0, stream>>>(Gt, WhhT + 4194304, Hbuf, Cbuf, nullptr, out,
                                      out + 16777216 + 131072, Bar);
}

// Round 2
// 5012.721 us; speedup vs baseline: 3.5760x; 3.5760x over previous
//
#include <hip/hip_runtime.h>

typedef unsigned short u16;
typedef unsigned int   u32;
typedef short bf16x8 __attribute__((ext_vector_type(8)));
typedef float f32x16 __attribute__((ext_vector_type(16)));

// Problem sizes: B=64, T=256, H=1024, L=2
static constexpr int TT = 256;

// Workspace layout (bytes). Total ~134.5 MB.
static constexpr size_t OFF_WCAT = 0;            // bf16 [2][4096 n_re][2048 kcat]  (Wih | Whh)
static constexpr size_t OFF_BIAS = 33554432;     // f32  [2][4096 n_re]  (bih+bhh)
static constexpr size_t OFF_XT   = 33587200;     // bf16 [256 t][64 b][1024 h]
static constexpr size_t OFF_HR0  = 67141632;     // bf16 [257][64][1024] layer-0 h ring
static constexpr size_t OFF_HR1  = 100827136;    // bf16 [257][64][1024] layer-1 h ring
static constexpr size_t OFF_FLG  = 134512640;    // int  [256][32] padded epoch flags

__device__ __forceinline__ u16 f2bf(float f) {
  u32 u = __float_as_uint(f);
  return (u16)((u + 0x7fffu + ((u >> 16) & 1u)) >> 16);  // RNE
}
__device__ __forceinline__ float sigm(float z) { return 1.f / (1.f + __expf(-z)); }
__device__ __forceinline__ float tanh_f(float z) {
  float e = __expf(fminf(fmaxf(2.f * z, -80.f), 80.f));
  return (e - 1.f) / (e + 1.f);
}

// unit reorder: gate col n = g*1024+u -> n_re = (u>>3)*32 + g*8 + (u&7)
// scan block lbid owns units [8*lbid, 8*lbid+8) = n_re rows [32*lbid, 32*lbid+32)

// ---------------- prep: transpose+reorder weights into Wcat[l][n_re][kcat] ----------------
__global__ void prep_transpose(const float* __restrict__ Wih, const float* __restrict__ Whh,
                               u16* __restrict__ Wcat) {
  __shared__ float tr[64][65];
  const int kt = blockIdx.x;            // 0..15 (k tiles of 64)
  const int nt = blockIdx.y;            // 0..63 (n tiles of 64)
  const int z  = blockIdx.z;            // 0:Wih L0, 1:Wih L1, 2:Whh L0, 3:Whh L1
  const float* src = (z < 2 ? Wih : Whh) + (size_t)(z & 1) * (1024 * 4096);
  u16* dst = Wcat + (size_t)(z & 1) * (4096 * 2048) + ((z < 2) ? 0 : 1024);
  const int tid = threadIdx.x;
  const int k0 = kt << 6, n0 = nt << 6;
#pragma unroll
  for (int i = 0; i < 16; ++i) {
    int e = (i << 8) + tid;
    int kk = e >> 6, nn = e & 63;
    tr[kk][nn] = src[(size_t)(k0 + kk) * 4096 + n0 + nn];
  }
  __syncthreads();
#pragma unroll
  for (int i = 0; i < 16; ++i) {
    int e = (i << 8) + tid;
    int nn = e >> 6, kk = e & 63;
    int n = n0 + nn;
    int u = n & 1023, g = n >> 10;
    int n_re = ((u >> 3) << 5) + (g << 3) + (u & 7);
    dst[(size_t)n_re * 2048 + k0 + kk] = f2bf(tr[kk][nn]);
  }
}

__global__ void prep_bias(const float* __restrict__ bih, const float* __restrict__ bhh,
                          float* __restrict__ biasr) {
  int i = blockIdx.x * 256 + threadIdx.x;   // 0..8191
  int l = i >> 12, n = i & 4095;
  int u = n & 1023, g = n >> 10;
  int n_re = ((u >> 3) << 5) + (g << 3) + (u & 7);
  biasr[(l << 12) + n_re] = bih[i] + bhh[i];
}

// cast + transpose x[b][t][h] f32 -> XT[t][b][h] bf16
__global__ void cast_xT(const float* __restrict__ x, u16* __restrict__ XT) {
  const int blk = blockIdx.x;           // b*256 + t
  const int b = blk >> 8, t = blk & 255;
  const float* src = x + ((size_t)blk << 10);
  u16* dst = XT + ((size_t)((t << 6) + b) << 10);
  int i = threadIdx.x << 2;
  float4 v = *(const float4*)(src + i);
  uint2 o;
  o.x = (u32)f2bf(v.x) | ((u32)f2bf(v.y) << 16);
  o.y = (u32)f2bf(v.z) | ((u32)f2bf(v.w) << 16);
  *(uint2*)(dst + i) = o;
}

// ---------------- coherent (cross-XCD) primitives ----------------
__device__ __forceinline__ void ld2_sc(const int* p0, const int* p1, int& r0, int& r1) {
  asm volatile("global_load_dword %0, %2, off sc0 sc1\n\t"
               "global_load_dword %1, %3, off sc0 sc1\n\t"
               "s_waitcnt vmcnt(0)"
               : "=&v"(r0), "=&v"(r1)
               : "v"(p0), "v"(p1)
               : "memory");
}
__device__ __forceinline__ void st_short_sc(u16* p, u32 v) {
  asm volatile("global_store_short %0, %1, off sc0 sc1" :: "v"(p), "v"(v) : "memory");
}

// ---------------- fused 2-layer pipelined persistent scan ----------------
// Grid 256 blocks x 512 thr, 1 block/CU (144KB LDS). layer = bid>>7, lbid = bid&127.
// Block owns 8 hidden units (32 reordered gate cols). Waves: kh(4) x mh(2):
//  kh 0,1 -> input GEMM k-halves (L0: x(t); L1: h0(t)), kh 2,3 -> recurrent k-halves.
// Wave tile: 32 batch x 32 cols, K=512, mfma_f32_32x32x16_bf16, B from swizzled LDS.
__global__ __launch_bounds__(512, 2)
void lstm_fused(const u16* __restrict__ XT, u16* __restrict__ HR0, u16* __restrict__ HR1,
                const u16* __restrict__ Wcat, const float* __restrict__ biasr,
                float* __restrict__ out, int* __restrict__ flags) {
  __shared__ __align__(16) u16 Bs[32 * 2048];   // 128 KB weight slice [32 n][2048 kcat], XOR-swizzled
  __shared__ float Gsh[2][64][32];              // 16 KB split-K combine

  const int bid = blockIdx.x;
  const int layer = bid >> 7;
  const int lbid = bid & 127;
  const int tid = threadIdx.x;
  const int lane = tid & 63;
  const int w = tid >> 6;
  const int kh = w >> 1, mh = w & 1;

  // ---- stage weight slice into LDS (swizzled: byte ^= (row&7)<<4) ----
  const u16* wsrc = Wcat + ((size_t)((layer << 12) + (lbid << 5))) * 2048;
#pragma unroll
  for (int i = 0; i < 16; ++i) {
    int e = (i << 9) + tid;          // 0..8191 chunks of 16B
    int byte = e << 4;
    int row = byte >> 12;
    int swz = (byte & 4095) ^ ((row & 7) << 4);
    *(int4*)(Bs + (((row << 12) + swz) >> 1)) = *(const int4*)(wsrc + (byte >> 1));
  }

  // ---- per-thread pointwise setup (c kept in register) ----
  const int pb = tid >> 3, pu = tid & 7;
  const float* bb = biasr + (layer << 12) + (lbid << 5);
  const float bi = bb[pu], bfv = bb[8 + pu], bg = bb[16 + pu], bo = bb[24 + pu];
  float creg = 0.f;
  const int uglob = (lbid << 3) + pu;

  // ---- GEMM addressing ----
  const u16* inring  = layer ? (HR0 + 65536) : XT;   // slot t (L1: h0(t) = HR0[t+1])
  const u16* recring = layer ? HR1 : HR0;
  u16*       outring = layer ? HR1 : HR0;
  const u16* aping = (kh < 2) ? inring : recring;
  const int mrow = (mh << 5) + (lane & 31);
  const int abase_off = mrow * 1024 + ((kh & 1) << 9) + ((lane >> 5) << 3);
  const int brow = lane & 31;
  const int bbase = (brow << 12) + (kh << 10) + ((lane >> 5) << 4);   // bytes
  const int xm = (brow & 7) << 4;

  // ---- flag polling setup ----
  // L0 kh<2: no poll. L0 kh>=2: f0>=t. L1 kh<2: f0>=t+1. L1 kh>=2: f1>=t.
  const bool needpoll = (layer == 1) || (kh >= 2);
  const int* fbase = (layer == 1 && kh >= 2) ? (flags + 4096) : flags;
  const int tadd = (layer == 1 && kh < 2) ? 1 : 0;
  int* ownflag = flags + (((layer << 7) + lbid) << 5);

  const int col = lane & 31;
  const int rb = (mh << 5) + ((lane >> 5) << 2);

  __syncthreads();

  for (int t = 0; t < TT; ++t) {
    if (needpoll) {
      const int tgt = t + tadd;
      const int* p0 = fbase + (lane << 5);
      const int* p1 = fbase + ((lane + 64) << 5);
      for (;;) {
        int v0, v1;
        ld2_sc(p0, p1, v0, v1);
        if (__all((v0 >= tgt) & (v1 >= tgt))) break;
        __builtin_amdgcn_s_sleep(2);
      }
      asm volatile("buffer_inv sc1" ::: "memory");   // acquire: drop possibly-stale lines
    }

    // ---- GEMM: 32 x (global A, LDS B, mfma), 2 acc chains ----
    const u16* ap = aping + (size_t)t * 65536 + abase_off;
    f32x16 ae = {}, ao = {};
#pragma unroll
    for (int kk = 0; kk < 32; kk += 2) {
      bf16x8 av0 = *(const bf16x8*)(ap + kk * 16);
      bf16x8 bv0 = *(const bf16x8*)(Bs + ((((bbase + kk * 32)) ^ xm) >> 1));
      bf16x8 av1 = *(const bf16x8*)(ap + kk * 16 + 16);
      bf16x8 bv1 = *(const bf16x8*)(Bs + ((((bbase + kk * 32 + 32)) ^ xm) >> 1));
      ae = __builtin_amdgcn_mfma_f32_32x32x16_bf16(av0, bv0, ae, 0, 0, 0);
      ao = __builtin_amdgcn_mfma_f32_32x32x16_bf16(av1, bv1, ao, 0, 0, 0);
    }
    f32x16 acc = ae + ao;

    // ---- split-K combine: kh even writes, kh odd adds ----
    if ((kh & 1) == 0) {
#pragma unroll
      for (int r = 0; r < 16; ++r)
        Gsh[kh >> 1][rb + (r & 3) + ((r >> 2) << 3)][col] = acc[r];
    }
    __syncthreads();
    if (kh & 1) {
#pragma unroll
      for (int r = 0; r < 16; ++r)
        Gsh[kh >> 1][rb + (r & 3) + ((r >> 2) << 3)][col] += acc[r];
    }
    __syncthreads();

    // ---- pointwise (1 (b,u) per thread), h published coherently ----
    {
      float zi = Gsh[0][pb][pu]      + Gsh[1][pb][pu]      + bi;
      float zf = Gsh[0][pb][8 + pu]  + Gsh[1][pb][8 + pu]  + bfv;
      float zg = Gsh[0][pb][16 + pu] + Gsh[1][pb][16 + pu] + bg;
      float zo = Gsh[0][pb][24 + pu] + Gsh[1][pb][24 + pu] + bo;
      creg = sigm(zf) * creg + sigm(zi) * tanh_f(zg);
      float hn = sigm(zo) * tanh_f(creg);
      st_short_sc(outring + (size_t)(t + 1) * 65536 + (pb << 10) + uglob, (u32)f2bf(hn));
      if (layer) out[((size_t)pb << 18) + (t << 10) + uglob] = hn;
      if (t == TT - 1) {
        float* st = out + 16777216 + layer * 131072;
        st[(pb << 10) + uglob] = hn;
        st[65536 + (pb << 10) + uglob] = creg;
      }
    }
    asm volatile("s_waitcnt vmcnt(0)" ::: "memory");  // drain h stores (asm stores invisible to compiler)
    __syncthreads();
    if (tid == 0) {
      int val = t + 1;
      asm volatile("global_store_dword %0, %1, off sc0 sc1\n\ts_waitcnt vmcnt(0)"
                   :: "v"(ownflag), "v"(val) : "memory");
    }
  }
}

extern "C" void kernel_launch(void* const* d_in, const int* in_sizes, int n_in,
                              void* d_out, int out_size, void* d_ws, size_t ws_size,
                              hipStream_t stream) {
  const float* x   = (const float*)d_in[0];
  const float* Wih = (const float*)d_in[1];
  const float* Whh = (const float*)d_in[2];
  const float* bih = (const float*)d_in[3];
  const float* bhh = (const float*)d_in[4];
  float* out = (float*)d_out;
  char* ws = (char*)d_ws;

  u16*   Wcat  = (u16*)(ws + OFF_WCAT);
  float* BiasR = (float*)(ws + OFF_BIAS);
  u16*   XT    = (u16*)(ws + OFF_XT);
  u16*   HR0   = (u16*)(ws + OFF_HR0);
  u16*   HR1   = (u16*)(ws + OFF_HR1);
  int*   Flg   = (int*)(ws + OFF_FLG);

  // zero: ring slot 0 (h(-1)=0) for both layers + epoch flags (ws is 0xAA-poisoned)
  hipMemsetAsync(ws + OFF_HR0, 0, 131072, stream);
  hipMemsetAsync(ws + OFF_HR1, 0, 131072, stream);
  hipMemsetAsync(ws + OFF_FLG, 0, 32768, stream);

  prep_transpose<<<dim3(16, 64, 4), 256, 0, stream>>>(Wih, Whh, Wcat);
  prep_bias<<<32, 256, 0, stream>>>(bih, bhh, BiasR);
  cast_xT<<<16384, 256, 0, stream>>>(x, XT);

  lstm_fused<<<256, 512, 0, stream>>>(XT, HR0, HR1, Wcat, BiasR, out, Flg);
}

// Round 3
// 2719.864 us; speedup vs baseline: 6.5906x; 1.8430x over previous
//
#include <hip/hip_runtime.h>

typedef unsigned short u16;
typedef unsigned int   u32;
typedef short bf16x8 __attribute__((ext_vector_type(8)));
typedef float f32x16 __attribute__((ext_vector_type(16)));

// Problem sizes: B=64, T=256, H=1024, L=2
static constexpr int TT = 256;

// Workspace layout (bytes). Total ~134.5 MB.
static constexpr size_t OFF_WCAT = 0;            // bf16 [2][4096 n_re][2048 kcat]  (Wih | Whh)
static constexpr size_t OFF_BIAS = 33554432;     // f32  [2][4096 n_re]  (bih+bhh)
static constexpr size_t OFF_XT   = 33587200;     // bf16 [256 t][64 b][1024 h]
static constexpr size_t OFF_HR0  = 67141632;     // bf16 [257][64][1024] layer-0 h ring
static constexpr size_t OFF_HR1  = 100827136;    // bf16 [257][64][1024] layer-1 h ring
static constexpr size_t OFF_FLG  = 134512640;    // int  [2][128][32] padded per-block flags

__device__ __forceinline__ u16 f2bf(float f) {
  u32 u = __float_as_uint(f);
  return (u16)((u + 0x7fffu + ((u >> 16) & 1u)) >> 16);  // RNE
}
__device__ __forceinline__ float sigm(float z) { return 1.f / (1.f + __expf(-z)); }
__device__ __forceinline__ float tanh_f(float z) {
  float e = __expf(fminf(fmaxf(2.f * z, -80.f), 80.f));
  return (e - 1.f) / (e + 1.f);
}

// unit reorder: gate col n = g*1024+u -> n_re = (u>>3)*32 + g*8 + (u&7)
// scan block lbid owns units [8*lbid, 8*lbid+8) = n_re rows [32*lbid, 32*lbid+32)

// ---------------- prep: transpose+reorder weights into Wcat[l][n_re][kcat] ----------------
__global__ void prep_transpose(const float* __restrict__ Wih, const float* __restrict__ Whh,
                               u16* __restrict__ Wcat) {
  __shared__ float tr[64][65];
  const int kt = blockIdx.x;            // 0..15
  const int nt = blockIdx.y;            // 0..63
  const int z  = blockIdx.z;            // 0:Wih L0, 1:Wih L1, 2:Whh L0, 3:Whh L1
  const float* src = (z < 2 ? Wih : Whh) + (size_t)(z & 1) * (1024 * 4096);
  u16* dst = Wcat + (size_t)(z & 1) * (4096 * 2048) + ((z < 2) ? 0 : 1024);
  const int tid = threadIdx.x;
  const int k0 = kt << 6, n0 = nt << 6;
#pragma unroll
  for (int i = 0; i < 16; ++i) {
    int e = (i << 8) + tid;
    int kk = e >> 6, nn = e & 63;
    tr[kk][nn] = src[(size_t)(k0 + kk) * 4096 + n0 + nn];
  }
  __syncthreads();
#pragma unroll
  for (int i = 0; i < 16; ++i) {
    int e = (i << 8) + tid;
    int nn = e >> 6, kk = e & 63;
    int n = n0 + nn;
    int u = n & 1023, g = n >> 10;
    int n_re = ((u >> 3) << 5) + (g << 3) + (u & 7);
    dst[(size_t)n_re * 2048 + k0 + kk] = f2bf(tr[kk][nn]);
  }
}

__global__ void prep_bias(const float* __restrict__ bih, const float* __restrict__ bhh,
                          float* __restrict__ biasr) {
  int i = blockIdx.x * 256 + threadIdx.x;   // 0..8191
  int l = i >> 12, n = i & 4095;
  int u = n & 1023, g = n >> 10;
  int n_re = ((u >> 3) << 5) + (g << 3) + (u & 7);
  biasr[(l << 12) + n_re] = bih[i] + bhh[i];
}

// cast + transpose x[b][t][h] f32 -> XT[t][b][h] bf16
__global__ void cast_xT(const float* __restrict__ x, u16* __restrict__ XT) {
  const int blk = blockIdx.x;           // b*256 + t
  const int b = blk >> 8, t = blk & 255;
  const float* src = x + ((size_t)blk << 10);
  u16* dst = XT + ((size_t)((t << 6) + b) << 10);
  int i = threadIdx.x << 2;
  float4 v = *(const float4*)(src + i);
  uint2 o;
  o.x = (u32)f2bf(v.x) | ((u32)f2bf(v.y) << 16);
  o.y = (u32)f2bf(v.z) | ((u32)f2bf(v.w) << 16);
  *(uint2*)(dst + i) = o;
}

// ---------------- coherent (cross-XCD) primitives ----------------
__device__ __forceinline__ void ld2_sc(const int* p0, const int* p1, int& r0, int& r1) {
  asm volatile("global_load_dword %0, %2, off sc0 sc1\n\t"
               "global_load_dword %1, %3, off sc0 sc1\n\t"
               "s_waitcnt vmcnt(0)"
               : "=&v"(r0), "=&v"(r1)
               : "v"(p0), "v"(p1)
               : "memory");
}
__device__ __forceinline__ void ld4_sc(const int* p0, const int* p1, const int* p2,
                                       const int* p3, int& r0, int& r1, int& r2, int& r3) {
  asm volatile("global_load_dword %0, %4, off sc0 sc1\n\t"
               "global_load_dword %1, %5, off sc0 sc1\n\t"
               "global_load_dword %2, %6, off sc0 sc1\n\t"
               "global_load_dword %3, %7, off sc0 sc1\n\t"
               "s_waitcnt vmcnt(0)"
               : "=&v"(r0), "=&v"(r1), "=&v"(r2), "=&v"(r3)
               : "v"(p0), "v"(p1), "v"(p2), "v"(p3)
               : "memory");
}
__device__ __forceinline__ void st_short_sc(u16* p, u32 v) {
  asm volatile("global_store_short %0, %1, off sc0 sc1" :: "v"(p), "v"(v) : "memory");
}

// ---------------- fused 2-layer pipelined persistent scan ----------------
// Grid 256 blocks x 512 thr, 1 block/CU (144KB LDS). layer = bid>>7, lbid = bid&127.
// Block owns 8 hidden units (32 reordered gate cols). Waves (kh,mh): kh 0,1 ->
// input GEMM k-halves (L0: x(t); L1: h0(t)), kh 2,3 -> recurrent k-halves.
// Wave tile: 32 batch x 32 cols, K=512, mfma_f32_32x32x16_bf16.
// B in LDS laid out [kstep(128)][row*2+half] x 16B -> wave reads are 1024B
// contiguous: conflict-free, zero inner-loop address math.
// Coherence: h stores write-through (sc0 sc1) + vmcnt drain + per-block flag
// (sc store); consumers poll flags with sc loads (wave 0 only), then read h
// with PLAIN cached loads -- safe because every h address is read only after
// its flag, so no cache can hold a pre-write copy. No buffer_inv anywhere.
__global__ __launch_bounds__(512, 2)
void lstm_fused(const u16* __restrict__ XT, u16* __restrict__ HR0, u16* __restrict__ HR1,
                const u16* __restrict__ Wcat, const float* __restrict__ biasr,
                float* __restrict__ out, int* __restrict__ flags) {
  __shared__ __align__(16) u16 Bs[32 * 2048];   // 128 KB weight slice, k-major tiled
  __shared__ float Gsh[2][64][32];              // 16 KB split-K combine

  const int bid = blockIdx.x;
  const int layer = bid >> 7;
  const int lbid = bid & 127;
  const int tid = threadIdx.x;
  const int lane = tid & 63;
  const int w = tid >> 6;
  const int kh = w >> 1, mh = w & 1;

  // ---- stage weight slice into LDS: chunk e (16B): row=e>>8, kc=e&255 ->
  // idx16 = (kc>>1)*64 + row*2 + (kc&1)  (i.e. [kstep][row*2+half]) ----
  const u16* wsrc = Wcat + ((size_t)((layer << 12) + (lbid << 5))) * 2048;
#pragma unroll
  for (int i = 0; i < 16; ++i) {
    int e = (i << 9) + tid;
    int row = e >> 8, kc = e & 255;
    int idx16 = ((kc >> 1) << 6) + (row << 1) + (kc & 1);
    *(int4*)(Bs + (idx16 << 3)) = *(const int4*)(wsrc + (e << 3));
  }

  // ---- per-thread pointwise setup (c kept in register) ----
  const int pb = tid >> 3, pu = tid & 7;
  const float* bbp = biasr + (layer << 12) + (lbid << 5);
  const float bi = bbp[pu], bfv = bbp[8 + pu], bg = bbp[16 + pu], bo = bbp[24 + pu];
  float creg = 0.f;
  const int uglob = (lbid << 3) + pu;

  // ---- GEMM addressing ----
  const u16* inring  = layer ? (HR0 + 65536) : XT;   // L1 in: h0(t) = HR0 slot t+1
  const u16* recring = layer ? HR1 : HR0;
  u16*       outring = layer ? HR1 : HR0;
  const u16* aping = (kh < 2) ? inring : recring;
  const int mrow = (mh << 5) + (lane & 31);
  const int abase_off = mrow * 1024 + ((kh & 1) << 9) + ((lane >> 5) << 3);
  const u16* bsbase = Bs + ((kh << 14)) + ((((lane & 31) << 1) + (lane >> 5)) << 3);
  //            kh*32 ksteps * 512 halves = kh<<14 ; lane part: (row*2+half)*8 halves

  const int col = lane & 31;
  const int rb = (mh << 5) + ((lane >> 5) << 2);

  // ---- flags ----
  int* fl0 = flags;                  // layer-0 flags [128][32]
  int* fl1 = flags + 4096;           // layer-1 flags
  int* ownflag = (layer ? fl1 : fl0) + (lbid << 5);

  __syncthreads();

  for (int t = 0; t < TT; ++t) {
    // ---- wave-0 polls flags, rest of block waits at the barrier ----
    if (w == 0) {
      if (layer == 0) {
        if (t > 0) {
          const int* p0 = fl0 + (lane << 5);
          const int* p1 = fl0 + ((lane + 64) << 5);
          for (;;) {
            int v0, v1;
            ld2_sc(p0, p1, v0, v1);
            if (__all((v0 >= t) & (v1 >= t))) break;
          }
        }
      } else {
        const int* p0 = fl0 + (lane << 5);
        const int* p1 = fl0 + ((lane + 64) << 5);
        const int* p2 = fl1 + (lane << 5);
        const int* p3 = fl1 + ((lane + 64) << 5);
        const int ti = t + 1;
        for (;;) {
          int v0, v1, v2, v3;
          ld4_sc(p0, p1, p2, p3, v0, v1, v2, v3);
          if (__all((v0 >= ti) & (v1 >= ti) & (v2 >= t) & (v3 >= t))) break;
        }
      }
    }
    __syncthreads();

    // ---- GEMM: 32 x (global A, LDS B, mfma), 2 acc chains ----
    const u16* ap = aping + (size_t)t * 65536 + abase_off;
    f32x16 ae = {}, ao = {};
#pragma unroll
    for (int kk = 0; kk < 32; kk += 2) {
      bf16x8 av0 = *(const bf16x8*)(ap + kk * 16);
      bf16x8 bv0 = *(const bf16x8*)(bsbase + kk * 512);
      bf16x8 av1 = *(const bf16x8*)(ap + kk * 16 + 16);
      bf16x8 bv1 = *(const bf16x8*)(bsbase + kk * 512 + 512);
      ae = __builtin_amdgcn_mfma_f32_32x32x16_bf16(av0, bv0, ae, 0, 0, 0);
      ao = __builtin_amdgcn_mfma_f32_32x32x16_bf16(av1, bv1, ao, 0, 0, 0);
    }
    f32x16 acc = ae + ao;

    // ---- split-K combine: kh even writes, kh odd adds ----
    if ((kh & 1) == 0) {
#pragma unroll
      for (int r = 0; r < 16; ++r)
        Gsh[kh >> 1][rb + (r & 3) + ((r >> 2) << 3)][col] = acc[r];
    }
    __syncthreads();
    if (kh & 1) {
#pragma unroll
      for (int r = 0; r < 16; ++r)
        Gsh[kh >> 1][rb + (r & 3) + ((r >> 2) << 3)][col] += acc[r];
    }
    __syncthreads();

    // ---- pointwise (1 (b,u) per thread), h published write-through ----
    {
      float zi = Gsh[0][pb][pu]      + Gsh[1][pb][pu]      + bi;
      float zf = Gsh[0][pb][8 + pu]  + Gsh[1][pb][8 + pu]  + bfv;
      float zg = Gsh[0][pb][16 + pu] + Gsh[1][pb][16 + pu] + bg;
      float zo = Gsh[0][pb][24 + pu] + Gsh[1][pb][24 + pu] + bo;
      creg = sigm(zf) * creg + sigm(zi) * tanh_f(zg);
      float hn = sigm(zo) * tanh_f(creg);
      st_short_sc(outring + (size_t)(t + 1) * 65536 + (pb << 10) + uglob, (u32)f2bf(hn));
      if (layer) out[((size_t)pb << 18) + (t << 10) + uglob] = hn;
      if (t == TT - 1) {
        float* st = out + 16777216 + layer * 131072;
        st[(pb << 10) + uglob] = hn;
        st[65536 + (pb << 10) + uglob] = creg;
      }
    }
    asm volatile("s_waitcnt vmcnt(0)" ::: "memory");  // drain write-through h stores
    __syncthreads();                                  // all waves drained
    if (tid == 0) {
      int val = t + 1;
      asm volatile("global_store_dword %0, %1, off sc0 sc1"
                   :: "v"(ownflag), "v"(val) : "memory");
    }
  }
}

extern "C" void kernel_launch(void* const* d_in, const int* in_sizes, int n_in,
                              void* d_out, int out_size, void* d_ws, size_t ws_size,
                              hipStream_t stream) {
  const float* x   = (const float*)d_in[0];
  const float* Wih = (const float*)d_in[1];
  const float* Whh = (const float*)d_in[2];
  const float* bih = (const float*)d_in[3];
  const float* bhh = (const float*)d_in[4];
  float* out = (float*)d_out;
  char* ws = (char*)d_ws;

  u16*   Wcat  = (u16*)(ws + OFF_WCAT);
  float* BiasR = (float*)(ws + OFF_BIAS);
  u16*   XT    = (u16*)(ws + OFF_XT);
  u16*   HR0   = (u16*)(ws + OFF_HR0);
  u16*   HR1   = (u16*)(ws + OFF_HR1);
  int*   Flg   = (int*)(ws + OFF_FLG);

  // zero: ring slot 0 (h(-1)=0) for both layers + flags (ws is 0xAA-poisoned)
  hipMemsetAsync(ws + OFF_HR0, 0, 131072, stream);
  hipMemsetAsync(ws + OFF_HR1, 0, 131072, stream);
  hipMemsetAsync(ws + OFF_FLG, 0, 32768, stream);

  prep_transpose<<<dim3(16, 64, 4), 256, 0, stream>>>(Wih, Whh, Wcat);
  prep_bias<<<32, 256, 0, stream>>>(bih, bhh, BiasR);
  cast_xT<<<16384, 256, 0, stream>>>(x, XT);

  lstm_fused<<<256, 512, 0, stream>>>(XT, HR0, HR1, Wcat, BiasR, out, Flg);
}